// Round 15
// baseline (173.001 us; speedup 1.0000x reference)
//
#include <hip/hip_runtime.h>

#define N_NODES  100000
#define N_EDGES  6400000
#define N_GRAPHS 64
#define SCAN_BS  1024
#define NRDF     100096              // deg: all nodes, u8 bins = 97.75 KB LDS
#define DEGW     (NRDF / 4)          // 25024 u32 words
#define NR2      50048               // acc1: nodes per block-group (2 groups)
#define LDSW     (NR2 / 2)           // 25024 u32 words (f16 pairs) = 97.75 KB
#define NR3      33344               // acc2: nodes per block-group (3 groups), 130.25 KB

// int64-layout detect: hi dwords of first 16 values all zero => stride 2.
__device__ __forceinline__ int idx_stride(const int* ei) {
    int allzero = 1;
    #pragma unroll
    for (int k = 0; k < 16; ++k)
        if (ei[2 * k + 1] != 0) allzero = 0;
    return allzero ? 2 : 1;
}

__device__ __forceinline__ void pk_add_f16(unsigned ldsBase, unsigned a, float v) {
    _Float16 h = (_Float16)v;
    unsigned hb = (unsigned)__builtin_bit_cast(unsigned short, h);
    unsigned pk = (a & 1) ? (hb << 16) : hb;
    unsigned addr = ldsBase + ((a >> 1) << 2);
    asm volatile("ds_pk_add_f16 %0, %1" :: "v"(addr), "v"(pk) : "memory");
}

// ================= PACKED PATH (ws >= ~89 MB) ============================
// One-time pack: int64 cols -> u32 dstc/srcc, FUSED with deg u8 binning.
__global__ __launch_bounds__(SCAN_BS)
void pack_deg(const int* ei, unsigned* dstc, unsigned* srcc,
              unsigned char* copies) {
    __shared__ unsigned bins[DEGW];
    for (int i = threadIdx.x; i < DEGW; i += SCAN_BS) bins[i] = 0u;
    __syncthreads();
    const int stride = idx_stride(ei);
    const int tid = blockIdx.x * SCAN_BS + threadIdx.x;
    const int nth = gridDim.x * SCAN_BS;
#define DEGADD(u) { unsigned a = (unsigned)(u); \
    if (a < NRDF) atomicAdd(&bins[a >> 2], 1u << (8 * (a & 3))); }
    if (stride == 2) {                      // int64: 2 edges per int4
        const int4* dp = (const int4*)(ei + (size_t)N_EDGES * 2);
        const int4* sp = (const int4*)ei;
        uint2* d2 = (uint2*)dstc;
        uint2* s2 = (uint2*)srcc;
        for (int q = tid; q < N_EDGES / 2; q += nth) {
            int4 dv = dp[q], sv = sp[q];
            DEGADD(dv.x); DEGADD(dv.z);
            d2[q] = make_uint2((unsigned)dv.x, (unsigned)dv.z);
            s2[q] = make_uint2((unsigned)sv.x, (unsigned)sv.z);
        }
    } else {                                // int32: straight column copy
        const int4* dp = (const int4*)(ei + (size_t)N_EDGES);
        const int4* sp = (const int4*)ei;
        int4* d4 = (int4*)dstc;
        int4* s4 = (int4*)srcc;
        for (int q = tid; q < N_EDGES / 4; q += nth) {
            int4 dv = dp[q], sv = sp[q];
            DEGADD(dv.x); DEGADD(dv.y); DEGADD(dv.z); DEGADD(dv.w);
            d4[q] = dv;
            s4[q] = sv;
        }
    }
#undef DEGADD
    __syncthreads();
    unsigned* my = (unsigned*)(copies + (size_t)blockIdx.x * NRDF);
    for (int i = threadIdx.x; i < DEGW; i += SCAN_BS) my[i] = bins[i];
}

// acc1 over packed u32 cols: 2 groups, f16-pair LDS bins
__global__ __launch_bounds__(SCAN_BS)
void acc1_scanP(const unsigned* dstc, const unsigned* srcc, const float* wx,
                int G, unsigned* copies) {
    __shared__ unsigned bins[LDSW];
    for (int i = threadIdx.x; i < LDSW; i += SCAN_BS) bins[i] = 0u;
    __syncthreads();
    const int grp = (blockIdx.x >= G) ? 1 : 0;
    const int lo = grp * NR2;
    const int lb = blockIdx.x - grp * G;
    const unsigned ldsBase = (unsigned)(uintptr_t)&bins[0];
    const int tid = lb * SCAN_BS + threadIdx.x;
    const int nth = G * SCAN_BS;
    const uint4* dp = (const uint4*)dstc;
    const uint4* sp = (const uint4*)srcc;
    const int lim = N_EDGES / 4;
    int q = tid;
    for (; q + nth < lim; q += 2 * nth) {
        uint4 d0 = dp[q], d1 = dp[q + nth];
        uint4 s0 = sp[q], s1 = sp[q + nth];
        unsigned a0 = d0.x - lo, a1 = d0.y - lo, a2 = d0.z - lo, a3 = d0.w - lo;
        unsigned a4 = d1.x - lo, a5 = d1.y - lo, a6 = d1.z - lo, a7 = d1.w - lo;
        float w0 = (a0 < NR2) ? wx[s0.x] : 0.0f;
        float w1 = (a1 < NR2) ? wx[s0.y] : 0.0f;
        float w2 = (a2 < NR2) ? wx[s0.z] : 0.0f;
        float w3 = (a3 < NR2) ? wx[s0.w] : 0.0f;
        float w4 = (a4 < NR2) ? wx[s1.x] : 0.0f;
        float w5 = (a5 < NR2) ? wx[s1.y] : 0.0f;
        float w6 = (a6 < NR2) ? wx[s1.z] : 0.0f;
        float w7 = (a7 < NR2) ? wx[s1.w] : 0.0f;
        if (a0 < NR2) pk_add_f16(ldsBase, a0, w0);
        if (a1 < NR2) pk_add_f16(ldsBase, a1, w1);
        if (a2 < NR2) pk_add_f16(ldsBase, a2, w2);
        if (a3 < NR2) pk_add_f16(ldsBase, a3, w3);
        if (a4 < NR2) pk_add_f16(ldsBase, a4, w4);
        if (a5 < NR2) pk_add_f16(ldsBase, a5, w5);
        if (a6 < NR2) pk_add_f16(ldsBase, a6, w6);
        if (a7 < NR2) pk_add_f16(ldsBase, a7, w7);
    }
    for (; q < lim; q += nth) {
        uint4 dv = dp[q]; uint4 sv = sp[q];
        unsigned a = dv.x - lo, b = dv.y - lo, c = dv.z - lo, d = dv.w - lo;
        if (a < NR2) pk_add_f16(ldsBase, a, wx[sv.x]);
        if (b < NR2) pk_add_f16(ldsBase, b, wx[sv.y]);
        if (c < NR2) pk_add_f16(ldsBase, c, wx[sv.z]);
        if (d < NR2) pk_add_f16(ldsBase, d, wx[sv.w]);
    }
    __syncthreads();
    unsigned* my = copies + (size_t)blockIdx.x * LDSW;
    for (int i = threadIdx.x; i < LDSW; i += SCAN_BS) my[i] = bins[i];
}

// acc2 over packed u32 cols: 3 groups, one pk_add (wy,wz) per edge
__global__ __launch_bounds__(SCAN_BS)
void acc2_scanP(const unsigned* dstc, const unsigned* srcc, const unsigned* pyz,
                int G, unsigned* copies) {
    __shared__ unsigned bins[NR3];
    for (int i = threadIdx.x; i < NR3; i += SCAN_BS) bins[i] = 0u;
    __syncthreads();
    const int grp = blockIdx.x / G;
    const int lo = grp * NR3;
    const int lb = blockIdx.x - grp * G;
    const unsigned ldsBase = (unsigned)(uintptr_t)&bins[0];
    const int tid = lb * SCAN_BS + threadIdx.x;
    const int nth = G * SCAN_BS;
#define PKW(addr_a, pk) asm volatile("ds_pk_add_f16 %0, %1" :: \
    "v"(ldsBase + ((addr_a) << 2)), "v"(pk) : "memory")
    const uint4* dp = (const uint4*)dstc;
    const uint4* sp = (const uint4*)srcc;
    const int lim = N_EDGES / 4;
    int q = tid;
    for (; q + nth < lim; q += 2 * nth) {
        uint4 d0 = dp[q], d1 = dp[q + nth];
        uint4 s0 = sp[q], s1 = sp[q + nth];
        unsigned a0 = d0.x - lo, a1 = d0.y - lo, a2 = d0.z - lo, a3 = d0.w - lo;
        unsigned a4 = d1.x - lo, a5 = d1.y - lo, a6 = d1.z - lo, a7 = d1.w - lo;
        unsigned p0 = (a0 < NR3) ? pyz[s0.x] : 0u;
        unsigned p1 = (a1 < NR3) ? pyz[s0.y] : 0u;
        unsigned p2 = (a2 < NR3) ? pyz[s0.z] : 0u;
        unsigned p3 = (a3 < NR3) ? pyz[s0.w] : 0u;
        unsigned p4 = (a4 < NR3) ? pyz[s1.x] : 0u;
        unsigned p5 = (a5 < NR3) ? pyz[s1.y] : 0u;
        unsigned p6 = (a6 < NR3) ? pyz[s1.z] : 0u;
        unsigned p7 = (a7 < NR3) ? pyz[s1.w] : 0u;
        if (a0 < NR3) PKW(a0, p0);
        if (a1 < NR3) PKW(a1, p1);
        if (a2 < NR3) PKW(a2, p2);
        if (a3 < NR3) PKW(a3, p3);
        if (a4 < NR3) PKW(a4, p4);
        if (a5 < NR3) PKW(a5, p5);
        if (a6 < NR3) PKW(a6, p6);
        if (a7 < NR3) PKW(a7, p7);
    }
    for (; q < lim; q += nth) {
        uint4 dv = dp[q]; uint4 sv = sp[q];
        unsigned a = dv.x - lo, b = dv.y - lo, c = dv.z - lo, d = dv.w - lo;
        if (a < NR3) { unsigned p = pyz[sv.x]; PKW(a, p); }
        if (b < NR3) { unsigned p = pyz[sv.y]; PKW(b, p); }
        if (c < NR3) { unsigned p = pyz[sv.z]; PKW(c, p); }
        if (d < NR3) { unsigned p = pyz[sv.w]; PKW(d, p); }
    }
#undef PKW
    __syncthreads();
    unsigned* my = copies + (size_t)blockIdx.x * NR3;
    for (int i = threadIdx.x; i < NR3; i += SCAN_BS) my[i] = bins[i];
}

// ================= FALLBACK PATH (r13 verbatim scans) ====================
__global__ __launch_bounds__(SCAN_BS)
void deg_scan(const int* ei, unsigned char* copies) {
    __shared__ unsigned bins[DEGW];
    for (int i = threadIdx.x; i < DEGW; i += SCAN_BS) bins[i] = 0u;
    __syncthreads();
    const int stride = idx_stride(ei);
    const int tid = blockIdx.x * SCAN_BS + threadIdx.x;
    const int nth = gridDim.x * SCAN_BS;
#define DEGADD(u) { unsigned a = (unsigned)(u); \
    if (a < NRDF) atomicAdd(&bins[a >> 2], 1u << (8 * (a & 3))); }
    if (stride == 2) {
        const int4* dp = (const int4*)(ei + (size_t)N_EDGES * 2);
        const int lim = N_EDGES / 2;
        int q = tid;
        for (; q + 7 * nth < lim; q += 8 * nth) {
            int4 v0 = dp[q],           v1 = dp[q + nth];
            int4 v2 = dp[q + 2 * nth], v3 = dp[q + 3 * nth];
            int4 v4 = dp[q + 4 * nth], v5 = dp[q + 5 * nth];
            int4 v6 = dp[q + 6 * nth], v7 = dp[q + 7 * nth];
            DEGADD(v0.x); DEGADD(v0.z); DEGADD(v1.x); DEGADD(v1.z);
            DEGADD(v2.x); DEGADD(v2.z); DEGADD(v3.x); DEGADD(v3.z);
            DEGADD(v4.x); DEGADD(v4.z); DEGADD(v5.x); DEGADD(v5.z);
            DEGADD(v6.x); DEGADD(v6.z); DEGADD(v7.x); DEGADD(v7.z);
        }
        for (; q < lim; q += nth) { int4 v = dp[q]; DEGADD(v.x); DEGADD(v.z); }
    } else {
        const int4* dp = (const int4*)(ei + (size_t)N_EDGES);
        for (int q = tid; q < N_EDGES / 4; q += nth) {
            int4 v = dp[q];
            DEGADD(v.x); DEGADD(v.y); DEGADD(v.z); DEGADD(v.w);
        }
    }
#undef DEGADD
    __syncthreads();
    unsigned* my = (unsigned*)(copies + (size_t)blockIdx.x * NRDF);
    for (int i = threadIdx.x; i < DEGW; i += SCAN_BS) my[i] = bins[i];
}

__global__ __launch_bounds__(SCAN_BS)
void acc1_scan(const int* ei, const float* wx, int G, unsigned* copies) {
    __shared__ unsigned bins[LDSW];
    for (int i = threadIdx.x; i < LDSW; i += SCAN_BS) bins[i] = 0u;
    __syncthreads();
    const int grp = (blockIdx.x >= G) ? 1 : 0;
    const int lo = grp * NR2;
    const int lb = blockIdx.x - grp * G;
    const unsigned ldsBase = (unsigned)(uintptr_t)&bins[0];
    const int stride = idx_stride(ei);
    const int tid = lb * SCAN_BS + threadIdx.x;
    const int nth = G * SCAN_BS;
    if (stride == 2) {
        const int4* sp = (const int4*)ei;
        const int4* dp = (const int4*)(ei + (size_t)N_EDGES * 2);
        const int lim = N_EDGES / 2;
        int q = tid;
        for (; q + 3 * nth < lim; q += 4 * nth) {
            int4 d0 = dp[q],           d1 = dp[q + nth];
            int4 d2 = dp[q + 2 * nth], d3 = dp[q + 3 * nth];
            int4 s0 = sp[q],           s1 = sp[q + nth];
            int4 s2 = sp[q + 2 * nth], s3 = sp[q + 3 * nth];
            unsigned a0 = (unsigned)(d0.x - lo), a1 = (unsigned)(d0.z - lo);
            unsigned a2 = (unsigned)(d1.x - lo), a3 = (unsigned)(d1.z - lo);
            unsigned a4 = (unsigned)(d2.x - lo), a5 = (unsigned)(d2.z - lo);
            unsigned a6 = (unsigned)(d3.x - lo), a7 = (unsigned)(d3.z - lo);
            float w0 = (a0 < NR2) ? wx[s0.x] : 0.0f;
            float w1 = (a1 < NR2) ? wx[s0.z] : 0.0f;
            float w2 = (a2 < NR2) ? wx[s1.x] : 0.0f;
            float w3 = (a3 < NR2) ? wx[s1.z] : 0.0f;
            float w4 = (a4 < NR2) ? wx[s2.x] : 0.0f;
            float w5 = (a5 < NR2) ? wx[s2.z] : 0.0f;
            float w6 = (a6 < NR2) ? wx[s3.x] : 0.0f;
            float w7 = (a7 < NR2) ? wx[s3.z] : 0.0f;
            if (a0 < NR2) pk_add_f16(ldsBase, a0, w0);
            if (a1 < NR2) pk_add_f16(ldsBase, a1, w1);
            if (a2 < NR2) pk_add_f16(ldsBase, a2, w2);
            if (a3 < NR2) pk_add_f16(ldsBase, a3, w3);
            if (a4 < NR2) pk_add_f16(ldsBase, a4, w4);
            if (a5 < NR2) pk_add_f16(ldsBase, a5, w5);
            if (a6 < NR2) pk_add_f16(ldsBase, a6, w6);
            if (a7 < NR2) pk_add_f16(ldsBase, a7, w7);
        }
        for (; q < lim; q += nth) {
            int4 dv = dp[q]; int4 sv = sp[q];
            unsigned a = (unsigned)(dv.x - lo), b = (unsigned)(dv.z - lo);
            if (a < NR2) pk_add_f16(ldsBase, a, wx[sv.x]);
            if (b < NR2) pk_add_f16(ldsBase, b, wx[sv.z]);
        }
    } else {
        const int4* sp = (const int4*)ei;
        const int4* dp = (const int4*)(ei + (size_t)N_EDGES);
        for (int q = tid; q < N_EDGES / 4; q += nth) {
            int4 dv = dp[q]; int4 sv = sp[q];
            unsigned a = (unsigned)(dv.x - lo), b = (unsigned)(dv.y - lo);
            unsigned c = (unsigned)(dv.z - lo), d = (unsigned)(dv.w - lo);
            if (a < NR2) pk_add_f16(ldsBase, a, wx[sv.x]);
            if (b < NR2) pk_add_f16(ldsBase, b, wx[sv.y]);
            if (c < NR2) pk_add_f16(ldsBase, c, wx[sv.z]);
            if (d < NR2) pk_add_f16(ldsBase, d, wx[sv.w]);
        }
    }
    __syncthreads();
    unsigned* my = copies + (size_t)blockIdx.x * LDSW;
    for (int i = threadIdx.x; i < LDSW; i += SCAN_BS) my[i] = bins[i];
}

__global__ __launch_bounds__(SCAN_BS)
void acc2_scan(const int* ei, const unsigned* pyz, int G, unsigned* copies) {
    __shared__ unsigned bins[NR3];
    for (int i = threadIdx.x; i < NR3; i += SCAN_BS) bins[i] = 0u;
    __syncthreads();
    const int grp = blockIdx.x / G;
    const int lo = grp * NR3;
    const int lb = blockIdx.x - grp * G;
    const unsigned ldsBase = (unsigned)(uintptr_t)&bins[0];
    const int stride = idx_stride(ei);
    const int tid = lb * SCAN_BS + threadIdx.x;
    const int nth = G * SCAN_BS;
#define PKW(addr_a, pk) asm volatile("ds_pk_add_f16 %0, %1" :: \
    "v"(ldsBase + ((addr_a) << 2)), "v"(pk) : "memory")
    if (stride == 2) {
        const int4* sp = (const int4*)ei;
        const int4* dp = (const int4*)(ei + (size_t)N_EDGES * 2);
        const int lim = N_EDGES / 2;
        int q = tid;
        for (; q + 3 * nth < lim; q += 4 * nth) {
            int4 d0 = dp[q],           d1 = dp[q + nth];
            int4 d2 = dp[q + 2 * nth], d3 = dp[q + 3 * nth];
            int4 s0 = sp[q],           s1 = sp[q + nth];
            int4 s2 = sp[q + 2 * nth], s3 = sp[q + 3 * nth];
            unsigned a0 = (unsigned)(d0.x - lo), a1 = (unsigned)(d0.z - lo);
            unsigned a2 = (unsigned)(d1.x - lo), a3 = (unsigned)(d1.z - lo);
            unsigned a4 = (unsigned)(d2.x - lo), a5 = (unsigned)(d2.z - lo);
            unsigned a6 = (unsigned)(d3.x - lo), a7 = (unsigned)(d3.z - lo);
            unsigned p0 = (a0 < NR3) ? pyz[s0.x] : 0u;
            unsigned p1 = (a1 < NR3) ? pyz[s0.z] : 0u;
            unsigned p2 = (a2 < NR3) ? pyz[s1.x] : 0u;
            unsigned p3 = (a3 < NR3) ? pyz[s1.z] : 0u;
            unsigned p4 = (a4 < NR3) ? pyz[s2.x] : 0u;
            unsigned p5 = (a5 < NR3) ? pyz[s2.z] : 0u;
            unsigned p6 = (a6 < NR3) ? pyz[s3.x] : 0u;
            unsigned p7 = (a7 < NR3) ? pyz[s3.z] : 0u;
            if (a0 < NR3) PKW(a0, p0);
            if (a1 < NR3) PKW(a1, p1);
            if (a2 < NR3) PKW(a2, p2);
            if (a3 < NR3) PKW(a3, p3);
            if (a4 < NR3) PKW(a4, p4);
            if (a5 < NR3) PKW(a5, p5);
            if (a6 < NR3) PKW(a6, p6);
            if (a7 < NR3) PKW(a7, p7);
        }
        for (; q < lim; q += nth) {
            int4 dv = dp[q]; int4 sv = sp[q];
            unsigned a = (unsigned)(dv.x - lo), b = (unsigned)(dv.z - lo);
            if (a < NR3) { unsigned p = pyz[sv.x]; PKW(a, p); }
            if (b < NR3) { unsigned p = pyz[sv.z]; PKW(b, p); }
        }
    } else {
        const int4* sp = (const int4*)ei;
        const int4* dp = (const int4*)(ei + (size_t)N_EDGES);
        for (int q = tid; q < N_EDGES / 4; q += nth) {
            int4 dv = dp[q]; int4 sv = sp[q];
            unsigned a = (unsigned)(dv.x - lo), b = (unsigned)(dv.y - lo);
            unsigned c = (unsigned)(dv.z - lo), d = (unsigned)(dv.w - lo);
            if (a < NR3) { unsigned p = pyz[sv.x]; PKW(a, p); }
            if (b < NR3) { unsigned p = pyz[sv.y]; PKW(b, p); }
            if (c < NR3) { unsigned p = pyz[sv.z]; PKW(c, p); }
            if (d < NR3) { unsigned p = pyz[sv.w]; PKW(d, p); }
        }
    }
#undef PKW
    __syncthreads();
    unsigned* my = copies + (size_t)blockIdx.x * NR3;
    for (int i = threadIdx.x; i < NR3; i += SCAN_BS) my[i] = bins[i];
}

// ================= shared merges / final =================================
__global__ void deg_merge(const unsigned char* copies, int C, const int* ei,
                          const float* x, const int* batch,
                          float* wx, float2* pbt) {
    __shared__ float red[256];
    int il = threadIdx.x & 63, cs = threadIdx.x >> 6;
    int gi = blockIdx.x * 64 + il;
    bool ok = (gi < N_NODES);
    float partial = 0.0f;
    if (ok)
        for (int c = cs; c < C; c += 4)
            partial += (float)copies[(size_t)c * NRDF + gi];
    red[threadIdx.x] = partial;
    __syncthreads();
    if (cs == 0 && ok) {
        float d = 1.0f + red[il] + red[64 + il] + red[128 + il] + red[192 + il];
        float di = rsqrtf(d);
        wx[gi] = di * x[gi];
        const int stride = idx_stride(ei);
        pbt[gi] = make_float2(di, (float)batch[(size_t)gi * stride]);
    }
}

__global__ void acc1_merge(const unsigned* copies, int G,
                           const float* wx, const float2* pbt,
                           float* y1, unsigned* pyz, float* gacc) {
    __shared__ float red[256];
    int t = threadIdx.x;
    if (blockIdx.x == 0 && t < 3 * N_GRAPHS) gacc[t] = 0.0f;
    int il = t & 63, cs = t >> 6;
    int gi = blockIdx.x * 64 + il;
    bool ok = (gi < N_NODES);
    float partial = 0.0f;
    int grp = (gi >= NR2) ? 1 : 0;
    int li  = gi - grp * NR2;
    if (ok) {
        int sh = 16 * (li & 1), w = li >> 1;
        const unsigned* base = copies + (size_t)grp * G * LDSW;
        for (int c = cs; c < G; c += 4) {
            unsigned u = (base[(size_t)c * LDSW + w] >> sh) & 0xFFFFu;
            partial += (float)__builtin_bit_cast(_Float16, (unsigned short)u);
        }
    }
    red[t] = partial;
    __syncthreads();
    if (cs == 0 && ok) {
        float a1 = red[il] + red[64 + il] + red[128 + il] + red[192 + il];
        float di = pbt[gi].x;
        float y1v = di * (a1 + wx[gi]);
        y1[gi] = y1v;
        _Float16 hy = (_Float16)(di * y1v);
        _Float16 hz = (_Float16)di;
        pyz[gi] = (unsigned)__builtin_bit_cast(unsigned short, hy)
                | ((unsigned)__builtin_bit_cast(unsigned short, hz) << 16);
    }
}

__global__ void acc2_merge(const unsigned* copies, int G,
                           const float* y1, const float2* pbt, float* gacc) {
    __shared__ float redY[256];
    __shared__ float redZ[256];
    __shared__ float bins[3 * N_GRAPHS];
    int t = threadIdx.x;
    for (int k = t; k < 3 * N_GRAPHS; k += 256) bins[k] = 0.0f;
    int il = t & 63, cs = t >> 6;
    int gi = blockIdx.x * 64 + il;
    bool ok = (gi < N_NODES);
    float pyv = 0.0f, pzv = 0.0f;
    if (ok) {
        int grp = gi / NR3;
        int li  = gi - grp * NR3;
        const unsigned* base = copies + (size_t)grp * G * NR3;
        for (int c = cs; c < G; c += 4) {
            unsigned u = base[(size_t)c * NR3 + li];
            pyv += (float)__builtin_bit_cast(_Float16, (unsigned short)(u & 0xFFFFu));
            pzv += (float)__builtin_bit_cast(_Float16, (unsigned short)(u >> 16));
        }
    }
    redY[t] = pyv;
    redZ[t] = pzv;
    __syncthreads();
    if (cs == 0 && ok) {
        float a2 = redY[il] + redY[64 + il] + redY[128 + il] + redY[192 + il];
        float az = redZ[il] + redZ[64 + il] + redZ[128 + il] + redZ[192 + il];
        float2 pb = pbt[gi];
        float di = pb.x;
        int g = (int)pb.y;
        float di2 = di * di;
        float yv = di * a2 + di2 * y1[gi];
        float zv = di * az + di2;
        atomicAdd(&bins[g], yv);
        atomicAdd(&bins[N_GRAPHS + g], zv);
        atomicAdd(&bins[2 * N_GRAPHS + g], 1.0f);
    }
    __syncthreads();
    for (int k = t; k < 3 * N_GRAPHS; k += 256)
        if (bins[k] != 0.0f) atomicAdd(&gacc[k], bins[k]);
}

__global__ void final_kernel(const float* W1, const float* b1, const float* W2,
                             const float* b2, const float* gacc, float* out) {
    int g = threadIdx.x;
    if (g >= N_GRAPHS) return;
    float w0 = 0.f, w1 = 0.f, c0 = 0.f, c1 = 0.f;
    for (int j = 0; j < 16; ++j) {
        float a = W2[2 * j], b = W2[2 * j + 1];
        w0 += W1[j] * a;  w1 += W1[j] * b;
        c0 += b1[j] * a;  c1 += b1[j] * b;
    }
    float sy  = gacc[g];
    float sz  = gacc[N_GRAPHS + g];
    float cnt = gacc[2 * N_GRAPHS + g];
    float inv = 1.0f / fmaxf(cnt, 1.0f);
    out[2 * g + 0] = (sy * w0 + sz * c0 + cnt * b2[0]) * inv;
    out[2 * g + 1] = (sy * w1 + sz * c1 + cnt * b2[1]) * inv;
}

extern "C" void kernel_launch(void* const* d_in, const int* in_sizes, int n_in,
                              void* d_out, int out_size, void* d_ws, size_t ws_size,
                              hipStream_t stream) {
    const float* x     = (const float*)d_in[0];
    const int*   ei    = (const int*)d_in[1];
    const int*   batch = (const int*)d_in[2];
    const float* W1    = (const float*)d_in[3];
    const float* b1    = (const float*)d_in[4];
    const float* W2    = (const float*)d_in[5];
    const float* b2    = (const float*)d_in[6];
    float* out = (float*)d_out;

    // ws: wx[N] | y1[N] | pbt[N]f2 | pyz[N]u32 | gacc+pad | [dstc|srcc] | copies
    float*    f    = (float*)d_ws;
    float*    wx   = f;
    float*    y1   = wx + N_NODES;
    float2*   pbt  = (float2*)(y1 + N_NODES);
    unsigned* pyz  = (unsigned*)(pbt + N_NODES);
    float*    gacc = (float*)(pyz + N_NODES);
    unsigned* after = (unsigned*)(gacc + 3 * N_GRAPHS + 16);

    const long fixedB = (5L * N_NODES + 3 * N_GRAPHS + 16) * 4;
    // Packed-path requirement: 2 u32 edge cols + biggest copies region.
    const long packedColsB = 2L * N_EDGES * 4;                    // 51.2 MB
    const long copiesMaxB  = 3L * 85 * NR3 * 4;                   // ~34 MB (acc2)
    const bool packed = (long)ws_size >= fixedB + packedColsB + copiesMaxB
                                         + (1L << 20);

    if (packed) {
        unsigned* dstc = after;
        unsigned* srcc = dstc + N_EDGES;
        unsigned* copies = srcc + N_EDGES;
        const int CD = 256, G1 = 128, G2 = 85;

        pack_deg<<<CD, SCAN_BS, 0, stream>>>(ei, dstc, srcc,
                                             (unsigned char*)copies);
        deg_merge<<<(N_NODES + 63) / 64, 256, 0, stream>>>(
            (const unsigned char*)copies, CD, ei, x, batch, wx, pbt);

        acc1_scanP<<<2 * G1, SCAN_BS, 0, stream>>>(dstc, srcc, wx, G1, copies);
        acc1_merge<<<(N_NODES + 63) / 64, 256, 0, stream>>>(
            copies, G1, wx, pbt, y1, pyz, gacc);

        acc2_scanP<<<3 * G2, SCAN_BS, 0, stream>>>(dstc, srcc, pyz, G2, copies);
        acc2_merge<<<(N_NODES + 63) / 64, 256, 0, stream>>>(
            copies, G2, y1, pbt, gacc);
    } else {
        unsigned* copies = after;
        long availB = (long)ws_size - fixedB;
        long CD = availB / NRDF;
        if (CD > 256) CD = 256; if (CD < 8) CD = 8;
        long G1 = availB / (2L * LDSW * 4);
        if (G1 > 128) G1 = 128; if (G1 < 4) G1 = 4;
        long G2 = availB / (3L * NR3 * 4);
        if (G2 > 85) G2 = 85; if (G2 < 4) G2 = 4;

        deg_scan<<<(int)CD, SCAN_BS, 0, stream>>>(ei, (unsigned char*)copies);
        deg_merge<<<(N_NODES + 63) / 64, 256, 0, stream>>>(
            (const unsigned char*)copies, (int)CD, ei, x, batch, wx, pbt);

        acc1_scan<<<(int)(2 * G1), SCAN_BS, 0, stream>>>(ei, wx, (int)G1, copies);
        acc1_merge<<<(N_NODES + 63) / 64, 256, 0, stream>>>(
            copies, (int)G1, wx, pbt, y1, pyz, gacc);

        acc2_scan<<<(int)(3 * G2), SCAN_BS, 0, stream>>>(ei, pyz, (int)G2, copies);
        acc2_merge<<<(N_NODES + 63) / 64, 256, 0, stream>>>(
            copies, (int)G2, y1, pbt, gacc);
    }
    final_kernel<<<1, 64, 0, stream>>>(W1, b1, W2, b2, gacc, out);
}

// Round 16
// 158.153 us; speedup vs baseline: 1.0939x; 1.0939x over previous
//
#include <hip/hip_runtime.h>

#define N_NODES  100000
#define N_EDGES  6400000
#define N_GRAPHS 64
#define SCAN_BS  1024
#define NRDF     100096              // deg: all nodes, u8 bins = 97.75 KB LDS
#define DEGW     (NRDF / 4)          // 25024 u32 words
#define NR2      50048               // acc1: nodes per block-group (2 groups)
#define LDSW     (NR2 / 2)           // 25024 u32 words (f16 pairs) = 97.75 KB
#define NR3      33344               // acc2: nodes per block-group (3 groups), 130.25 KB

// int64-layout detect: hi dwords of first 16 values all zero => stride 2.
__device__ __forceinline__ int idx_stride(const int* ei) {
    int allzero = 1;
    #pragma unroll
    for (int k = 0; k < 16; ++k)
        if (ei[2 * k + 1] != 0) allzero = 0;
    return allzero ? 2 : 1;
}

__device__ __forceinline__ void pk_add_f16(unsigned ldsBase, unsigned a, float v) {
    _Float16 h = (_Float16)v;
    unsigned hb = (unsigned)__builtin_bit_cast(unsigned short, h);
    unsigned pk = (a & 1) ? (hb << 16) : hb;
    unsigned addr = ldsBase + ((a >> 1) << 2);
    asm volatile("ds_pk_add_f16 %0, %1" :: "v"(addr), "v"(pk) : "memory");
}

// ---------------- stage 1: degree, ONE scan, u8-packed LDS bins ----------
__global__ __launch_bounds__(SCAN_BS)
void deg_scan(const int* ei, unsigned char* copies) {
    __shared__ unsigned bins[DEGW];
    for (int i = threadIdx.x; i < DEGW; i += SCAN_BS) bins[i] = 0u;
    __syncthreads();
    const int stride = idx_stride(ei);
    const int tid = blockIdx.x * SCAN_BS + threadIdx.x;
    const int nth = gridDim.x * SCAN_BS;
#define DEGADD(u) { unsigned a = (unsigned)(u); \
    if (a < NRDF) atomicAdd(&bins[a >> 2], 1u << (8 * (a & 3))); }
    if (stride == 2) {                      // int64 dst col: 2 edges / int4
        const int4* dp = (const int4*)(ei + (size_t)N_EDGES * 2);
        const int lim = N_EDGES / 2;
        int q = tid;
        for (; q + 7 * nth < lim; q += 8 * nth) {
            int4 v0 = dp[q],           v1 = dp[q + nth];
            int4 v2 = dp[q + 2 * nth], v3 = dp[q + 3 * nth];
            int4 v4 = dp[q + 4 * nth], v5 = dp[q + 5 * nth];
            int4 v6 = dp[q + 6 * nth], v7 = dp[q + 7 * nth];
            DEGADD(v0.x); DEGADD(v0.z); DEGADD(v1.x); DEGADD(v1.z);
            DEGADD(v2.x); DEGADD(v2.z); DEGADD(v3.x); DEGADD(v3.z);
            DEGADD(v4.x); DEGADD(v4.z); DEGADD(v5.x); DEGADD(v5.z);
            DEGADD(v6.x); DEGADD(v6.z); DEGADD(v7.x); DEGADD(v7.z);
        }
        for (; q < lim; q += nth) { int4 v = dp[q]; DEGADD(v.x); DEGADD(v.z); }
    } else {                                // int32 dst col: 4 edges / int4
        const int4* dp = (const int4*)(ei + (size_t)N_EDGES);
        for (int q = tid; q < N_EDGES / 4; q += nth) {
            int4 v = dp[q];
            DEGADD(v.x); DEGADD(v.y); DEGADD(v.z); DEGADD(v.w);
        }
    }
#undef DEGADD
    __syncthreads();
    unsigned* my = (unsigned*)(copies + (size_t)blockIdx.x * NRDF);
    for (int i = threadIdx.x; i < DEGW; i += SCAN_BS) my[i] = bins[i];
}

// merge C u8 copies -> dinv; wx = dinv*x, pbt = (dinv, batch)
__global__ void deg_merge(const unsigned char* copies, int C, const int* ei,
                          const float* x, const int* batch,
                          float* wx, float2* pbt) {
    __shared__ float red[256];
    int il = threadIdx.x & 63, cs = threadIdx.x >> 6;
    int gi = blockIdx.x * 64 + il;
    bool ok = (gi < N_NODES);
    float partial = 0.0f;
    if (ok)
        for (int c = cs; c < C; c += 4)
            partial += (float)copies[(size_t)c * NRDF + gi];
    red[threadIdx.x] = partial;
    __syncthreads();
    if (cs == 0 && ok) {
        float d = 1.0f + red[il] + red[64 + il] + red[128 + il] + red[192 + il];
        float di = rsqrtf(d);
        wx[gi] = di * x[gi];
        const int stride = idx_stride(ei);
        pbt[gi] = make_float2(di, (float)batch[(size_t)gi * stride]);
    }
}

// ---------------- stage 2: acc1, 2 groups, f16 LDS bins ------------------
__global__ __launch_bounds__(SCAN_BS)
void acc1_scan(const int* ei, const float* wx, int G, unsigned* copies) {
    __shared__ unsigned bins[LDSW];
    for (int i = threadIdx.x; i < LDSW; i += SCAN_BS) bins[i] = 0u;
    __syncthreads();
    const int grp = (blockIdx.x >= G) ? 1 : 0;
    const int lo = grp * NR2;
    const int lb = blockIdx.x - grp * G;
    const unsigned ldsBase = (unsigned)(uintptr_t)&bins[0];
    const int stride = idx_stride(ei);
    const int tid = lb * SCAN_BS + threadIdx.x;
    const int nth = G * SCAN_BS;            // per-group stride: covers ALL edges
    if (stride == 2) {
        const int4* sp = (const int4*)ei;
        const int4* dp = (const int4*)(ei + (size_t)N_EDGES * 2);
        const int lim = N_EDGES / 2;
        int q = tid;
        for (; q + 3 * nth < lim; q += 4 * nth) {
            int4 d0 = dp[q],           d1 = dp[q + nth];
            int4 d2 = dp[q + 2 * nth], d3 = dp[q + 3 * nth];
            int4 s0 = sp[q],           s1 = sp[q + nth];
            int4 s2 = sp[q + 2 * nth], s3 = sp[q + 3 * nth];
            unsigned a0 = (unsigned)(d0.x - lo), a1 = (unsigned)(d0.z - lo);
            unsigned a2 = (unsigned)(d1.x - lo), a3 = (unsigned)(d1.z - lo);
            unsigned a4 = (unsigned)(d2.x - lo), a5 = (unsigned)(d2.z - lo);
            unsigned a6 = (unsigned)(d3.x - lo), a7 = (unsigned)(d3.z - lo);
            float w0 = (a0 < NR2) ? wx[s0.x] : 0.0f;
            float w1 = (a1 < NR2) ? wx[s0.z] : 0.0f;
            float w2 = (a2 < NR2) ? wx[s1.x] : 0.0f;
            float w3 = (a3 < NR2) ? wx[s1.z] : 0.0f;
            float w4 = (a4 < NR2) ? wx[s2.x] : 0.0f;
            float w5 = (a5 < NR2) ? wx[s2.z] : 0.0f;
            float w6 = (a6 < NR2) ? wx[s3.x] : 0.0f;
            float w7 = (a7 < NR2) ? wx[s3.z] : 0.0f;
            if (a0 < NR2) pk_add_f16(ldsBase, a0, w0);
            if (a1 < NR2) pk_add_f16(ldsBase, a1, w1);
            if (a2 < NR2) pk_add_f16(ldsBase, a2, w2);
            if (a3 < NR2) pk_add_f16(ldsBase, a3, w3);
            if (a4 < NR2) pk_add_f16(ldsBase, a4, w4);
            if (a5 < NR2) pk_add_f16(ldsBase, a5, w5);
            if (a6 < NR2) pk_add_f16(ldsBase, a6, w6);
            if (a7 < NR2) pk_add_f16(ldsBase, a7, w7);
        }
        for (; q < lim; q += nth) {
            int4 dv = dp[q]; int4 sv = sp[q];
            unsigned a = (unsigned)(dv.x - lo), b = (unsigned)(dv.z - lo);
            if (a < NR2) pk_add_f16(ldsBase, a, wx[sv.x]);
            if (b < NR2) pk_add_f16(ldsBase, b, wx[sv.z]);
        }
    } else {
        const int4* sp = (const int4*)ei;
        const int4* dp = (const int4*)(ei + (size_t)N_EDGES);
        for (int q = tid; q < N_EDGES / 4; q += nth) {
            int4 dv = dp[q]; int4 sv = sp[q];
            unsigned a = (unsigned)(dv.x - lo), b = (unsigned)(dv.y - lo);
            unsigned c = (unsigned)(dv.z - lo), d = (unsigned)(dv.w - lo);
            if (a < NR2) pk_add_f16(ldsBase, a, wx[sv.x]);
            if (b < NR2) pk_add_f16(ldsBase, b, wx[sv.y]);
            if (c < NR2) pk_add_f16(ldsBase, c, wx[sv.z]);
            if (d < NR2) pk_add_f16(ldsBase, d, wx[sv.w]);
        }
    }
    __syncthreads();
    unsigned* my = copies + (size_t)blockIdx.x * LDSW;
    for (int i = threadIdx.x; i < LDSW; i += SCAN_BS) my[i] = bins[i];
}

// merge acc1 copies -> y1 (f32), pyz = packed (f16 dinv*y1, f16 dinv);
// block 0 also zeroes gacc (only acc2_merge accumulates it, strictly later).
__global__ void acc1_merge(const unsigned* copies, int G,
                           const float* wx, const float2* pbt,
                           float* y1, unsigned* pyz, float* gacc) {
    __shared__ float red[256];
    int t = threadIdx.x;
    if (blockIdx.x == 0 && t < 3 * N_GRAPHS) gacc[t] = 0.0f;
    int il = t & 63, cs = t >> 6;
    int gi = blockIdx.x * 64 + il;
    bool ok = (gi < N_NODES);
    float partial = 0.0f;
    int grp = (gi >= NR2) ? 1 : 0;
    int li  = gi - grp * NR2;
    if (ok) {
        int sh = 16 * (li & 1), w = li >> 1;
        const unsigned* base = copies + (size_t)grp * G * LDSW;
        for (int c = cs; c < G; c += 4) {
            unsigned u = (base[(size_t)c * LDSW + w] >> sh) & 0xFFFFu;
            partial += (float)__builtin_bit_cast(_Float16, (unsigned short)u);
        }
    }
    red[t] = partial;
    __syncthreads();
    if (cs == 0 && ok) {
        float a1 = red[il] + red[64 + il] + red[128 + il] + red[192 + il];
        float di = pbt[gi].x;
        float y1v = di * (a1 + wx[gi]);       // dinv*(acc1 + dinv*x)
        y1[gi] = y1v;
        _Float16 hy = (_Float16)(di * y1v);   // wy = dinv*y1
        _Float16 hz = (_Float16)di;           // wz = dinv
        pyz[gi] = (unsigned)__builtin_bit_cast(unsigned short, hy)
                | ((unsigned)__builtin_bit_cast(unsigned short, hz) << 16);
    }
}

// ---------------- stage 3: acc2/accz scatter, 3 groups -------------------
__global__ __launch_bounds__(SCAN_BS)
void acc2_scan(const int* ei, const unsigned* pyz, int G, unsigned* copies) {
    __shared__ unsigned bins[NR3];          // u32 = (f16 wy-sum, f16 wz-sum)
    for (int i = threadIdx.x; i < NR3; i += SCAN_BS) bins[i] = 0u;
    __syncthreads();
    const int grp = blockIdx.x / G;         // 0,1,2
    const int lo = grp * NR3;
    const int lb = blockIdx.x - grp * G;
    const unsigned ldsBase = (unsigned)(uintptr_t)&bins[0];
    const int stride = idx_stride(ei);
    const int tid = lb * SCAN_BS + threadIdx.x;
    const int nth = G * SCAN_BS;
#define PKW(addr_a, pk) asm volatile("ds_pk_add_f16 %0, %1" :: \
    "v"(ldsBase + ((addr_a) << 2)), "v"(pk) : "memory")
    if (stride == 2) {
        const int4* sp = (const int4*)ei;
        const int4* dp = (const int4*)(ei + (size_t)N_EDGES * 2);
        const int lim = N_EDGES / 2;
        int q = tid;
        for (; q + 3 * nth < lim; q += 4 * nth) {
            int4 d0 = dp[q],           d1 = dp[q + nth];
            int4 d2 = dp[q + 2 * nth], d3 = dp[q + 3 * nth];
            int4 s0 = sp[q],           s1 = sp[q + nth];
            int4 s2 = sp[q + 2 * nth], s3 = sp[q + 3 * nth];
            unsigned a0 = (unsigned)(d0.x - lo), a1 = (unsigned)(d0.z - lo);
            unsigned a2 = (unsigned)(d1.x - lo), a3 = (unsigned)(d1.z - lo);
            unsigned a4 = (unsigned)(d2.x - lo), a5 = (unsigned)(d2.z - lo);
            unsigned a6 = (unsigned)(d3.x - lo), a7 = (unsigned)(d3.z - lo);
            unsigned p0 = (a0 < NR3) ? pyz[s0.x] : 0u;
            unsigned p1 = (a1 < NR3) ? pyz[s0.z] : 0u;
            unsigned p2 = (a2 < NR3) ? pyz[s1.x] : 0u;
            unsigned p3 = (a3 < NR3) ? pyz[s1.z] : 0u;
            unsigned p4 = (a4 < NR3) ? pyz[s2.x] : 0u;
            unsigned p5 = (a5 < NR3) ? pyz[s2.z] : 0u;
            unsigned p6 = (a6 < NR3) ? pyz[s3.x] : 0u;
            unsigned p7 = (a7 < NR3) ? pyz[s3.z] : 0u;
            if (a0 < NR3) PKW(a0, p0);
            if (a1 < NR3) PKW(a1, p1);
            if (a2 < NR3) PKW(a2, p2);
            if (a3 < NR3) PKW(a3, p3);
            if (a4 < NR3) PKW(a4, p4);
            if (a5 < NR3) PKW(a5, p5);
            if (a6 < NR3) PKW(a6, p6);
            if (a7 < NR3) PKW(a7, p7);
        }
        for (; q < lim; q += nth) {
            int4 dv = dp[q]; int4 sv = sp[q];
            unsigned a = (unsigned)(dv.x - lo), b = (unsigned)(dv.z - lo);
            if (a < NR3) { unsigned p = pyz[sv.x]; PKW(a, p); }
            if (b < NR3) { unsigned p = pyz[sv.z]; PKW(b, p); }
        }
    } else {
        const int4* sp = (const int4*)ei;
        const int4* dp = (const int4*)(ei + (size_t)N_EDGES);
        for (int q = tid; q < N_EDGES / 4; q += nth) {
            int4 dv = dp[q]; int4 sv = sp[q];
            unsigned a = (unsigned)(dv.x - lo), b = (unsigned)(dv.y - lo);
            unsigned c = (unsigned)(dv.z - lo), d = (unsigned)(dv.w - lo);
            if (a < NR3) { unsigned p = pyz[sv.x]; PKW(a, p); }
            if (b < NR3) { unsigned p = pyz[sv.y]; PKW(b, p); }
            if (c < NR3) { unsigned p = pyz[sv.z]; PKW(c, p); }
            if (d < NR3) { unsigned p = pyz[sv.w]; PKW(d, p); }
        }
    }
#undef PKW
    __syncthreads();
    unsigned* my = copies + (size_t)blockIdx.x * NR3;
    for (int i = threadIdx.x; i < NR3; i += SCAN_BS) my[i] = bins[i];
}

// merge acc2 copies; pool Sy/Sz/count (incl. self-loop) into gacc
__global__ void acc2_merge(const unsigned* copies, int G,
                           const float* y1, const float2* pbt, float* gacc) {
    __shared__ float redY[256];
    __shared__ float redZ[256];
    __shared__ float bins[3 * N_GRAPHS];
    int t = threadIdx.x;
    for (int k = t; k < 3 * N_GRAPHS; k += 256) bins[k] = 0.0f;
    int il = t & 63, cs = t >> 6;
    int gi = blockIdx.x * 64 + il;
    bool ok = (gi < N_NODES);
    float pyv = 0.0f, pzv = 0.0f;
    if (ok) {
        int grp = gi / NR3;
        int li  = gi - grp * NR3;
        const unsigned* base = copies + (size_t)grp * G * NR3;
        for (int c = cs; c < G; c += 4) {
            unsigned u = base[(size_t)c * NR3 + li];
            pyv += (float)__builtin_bit_cast(_Float16, (unsigned short)(u & 0xFFFFu));
            pzv += (float)__builtin_bit_cast(_Float16, (unsigned short)(u >> 16));
        }
    }
    redY[t] = pyv;
    redZ[t] = pzv;
    __syncthreads();
    if (cs == 0 && ok) {
        float a2 = redY[il] + redY[64 + il] + redY[128 + il] + redY[192 + il];
        float az = redZ[il] + redZ[64 + il] + redZ[128 + il] + redZ[192 + il];
        float2 pb = pbt[gi];
        float di = pb.x;
        int g = (int)pb.y;
        float di2 = di * di;
        float yv = di * a2 + di2 * y1[gi];   // (A_hat^2 x)_i incl. self-loop
        float zv = di * az + di2;            // (A_hat 1)_i incl. self-loop
        atomicAdd(&bins[g], yv);
        atomicAdd(&bins[N_GRAPHS + g], zv);
        atomicAdd(&bins[2 * N_GRAPHS + g], 1.0f);
    }
    __syncthreads();
    for (int k = t; k < 3 * N_GRAPHS; k += 256)
        if (bins[k] != 0.0f) atomicAdd(&gacc[k], bins[k]);
}

// ---------------- final --------------------------------------------------
__global__ void final_kernel(const float* W1, const float* b1, const float* W2,
                             const float* b2, const float* gacc, float* out) {
    int g = threadIdx.x;
    if (g >= N_GRAPHS) return;
    float w0 = 0.f, w1 = 0.f, c0 = 0.f, c1 = 0.f;
    for (int j = 0; j < 16; ++j) {
        float a = W2[2 * j], b = W2[2 * j + 1];
        w0 += W1[j] * a;  w1 += W1[j] * b;
        c0 += b1[j] * a;  c1 += b1[j] * b;
    }
    float sy  = gacc[g];
    float sz  = gacc[N_GRAPHS + g];
    float cnt = gacc[2 * N_GRAPHS + g];
    float inv = 1.0f / fmaxf(cnt, 1.0f);
    out[2 * g + 0] = (sy * w0 + sz * c0 + cnt * b2[0]) * inv;
    out[2 * g + 1] = (sy * w1 + sz * c1 + cnt * b2[1]) * inv;
}

extern "C" void kernel_launch(void* const* d_in, const int* in_sizes, int n_in,
                              void* d_out, int out_size, void* d_ws, size_t ws_size,
                              hipStream_t stream) {
    const float* x     = (const float*)d_in[0];
    const int*   ei    = (const int*)d_in[1];
    const int*   batch = (const int*)d_in[2];
    const float* W1    = (const float*)d_in[3];
    const float* b1    = (const float*)d_in[4];
    const float* W2    = (const float*)d_in[5];
    const float* b2    = (const float*)d_in[6];
    float* out = (float*)d_out;

    // ws: wx[N] | y1[N] | pbt[N]f2 | pyz[N]u32 | gacc+pad | copies
    float*    f    = (float*)d_ws;
    float*    wx   = f;
    float*    y1   = wx + N_NODES;
    float2*   pbt  = (float2*)(y1 + N_NODES);
    unsigned* pyz  = (unsigned*)(pbt + N_NODES);
    float*    gacc = (float*)(pyz + N_NODES);
    unsigned* copies = (unsigned*)(gacc + 3 * N_GRAPHS + 16);

    const long fixedB = (5L * N_NODES + 3 * N_GRAPHS + 16) * 4;
    long availB = (long)ws_size - fixedB;
    long CD = availB / NRDF;                // deg u8 copies
    if (CD > 256) CD = 256; if (CD < 8) CD = 8;
    long G1 = availB / (2L * LDSW * 4);     // acc1 copies per group
    if (G1 > 128) G1 = 128; if (G1 < 4) G1 = 4;
    long G2 = availB / (3L * NR3 * 4);      // acc2 copies per group
    if (G2 > 85) G2 = 85; if (G2 < 4) G2 = 4;

    deg_scan<<<(int)CD, SCAN_BS, 0, stream>>>(ei, (unsigned char*)copies);
    deg_merge<<<(N_NODES + 63) / 64, 256, 0, stream>>>(
        (const unsigned char*)copies, (int)CD, ei, x, batch, wx, pbt);

    acc1_scan<<<(int)(2 * G1), SCAN_BS, 0, stream>>>(ei, wx, (int)G1, copies);
    acc1_merge<<<(N_NODES + 63) / 64, 256, 0, stream>>>(
        copies, (int)G1, wx, pbt, y1, pyz, gacc);

    acc2_scan<<<(int)(3 * G2), SCAN_BS, 0, stream>>>(ei, pyz, (int)G2, copies);
    acc2_merge<<<(N_NODES + 63) / 64, 256, 0, stream>>>(
        copies, (int)G2, y1, pbt, gacc);

    final_kernel<<<1, 64, 0, stream>>>(W1, b1, W2, b2, gacc, out);
}